// Round 10
// baseline (5496.721 us; speedup 1.0000x reference)
//
#include <hip/hip_runtime.h>
#include <math.h>

#define TT 2048
#define BB 32
#define HH 512

// ---------------- input-projection GEMM: OUT[r,:] = X[r,:]@W + bias ----------------
template<int K>
__global__ void __launch_bounds__(256)
ih_gemm(const float* X, const float* __restrict__ W,
        const float* __restrict__ bias, float* OUT)
{
    __shared__ float xt[32][K];
    const int wg  = (int)blockIdx.x;
    const int tid = (int)threadIdx.x;
    const long row0 = (long)wg * 32;

    {   // stage 32 rows of X (coalesced float4)
        const float4* Xv = (const float4*)(X + row0 * K);
        float4* xtv = (float4*)(&xt[0][0]);
        const int n4 = 8 * K;
        for (int i = tid; i < n4; i += 256) xtv[i] = Xv[i];
    }
    __syncthreads();

    const int j2 = tid * 2;
    float acc0[32], acc1[32];
    #pragma unroll
    for (int r = 0; r < 32; ++r) { acc0[r] = 0.f; acc1[r] = 0.f; }

    for (int k = 0; k < K; k += 4) {
        const float2 w0 = *(const float2*)&W[(k+0)*HH + j2];
        const float2 w1 = *(const float2*)&W[(k+1)*HH + j2];
        const float2 w2 = *(const float2*)&W[(k+2)*HH + j2];
        const float2 w3 = *(const float2*)&W[(k+3)*HH + j2];
        #pragma unroll
        for (int r = 0; r < 32; ++r) {
            const float4 xv = *(const float4*)&xt[r][k];
            acc0[r] += xv.x*w0.x + xv.y*w1.x + xv.z*w2.x + xv.w*w3.x;
            acc1[r] += xv.x*w0.y + xv.y*w1.y + xv.z*w2.y + xv.w*w3.y;
        }
    }
    const float2 bv = *(const float2*)&bias[j2];
    #pragma unroll
    for (int r = 0; r < 32; ++r) {
        float2 o; o.x = acc0[r] + bv.x; o.y = acc1[r] + bv.y;
        *(float2*)&OUT[(row0 + r) * HH + j2] = o;
    }
}

// ---------------- fused 2-layer persistent recurrence ----------------
// Round-9 schedule (PASSED; tag-chain + parity-LDS proofs unchanged):
//   body(t): P3 poll h0[t] -> C1: Whh0-MAC+reduce+pub h0[t+1] (critical chain)
//            P2 poll h1[t-1] (1-step slack) -> C2: Wih1/Whh1-MAC+reduce -> h1[t]
// Round-9 failure: 192 pinned arch-VGPR W values -> allocator spilled ~100 to
// L2 scratch (VGPR_Count 112, FETCH +72MB, 2x superstep time).
// Fix: Wih1+Whh1 (C2 operands, latency-tolerant) live in 128 AGPRs via explicit
// v_accvgpr_write/read (gfx950 unified file: 256 regs/thread at 2 waves/EU, so
// ~100 arch + 128 acc fits). Whh0 (critical C1) stays in 64 pinned arch VGPRs
// (proven resident at this count in round 8). C2 pays +128 accvgpr_read (~256cy)
// inside the RTT slack window.
static __device__ __forceinline__ float tanhx(float s) {
    const float e = __expf(2.0f * s);
    return 1.0f - 2.0f / (e + 1.0f);
}
static __device__ __forceinline__ void pub(unsigned long long* p, unsigned tag, float v) {
    __hip_atomic_store(p, ((unsigned long long)tag << 32) | (unsigned long long)__float_as_uint(v),
                       __ATOMIC_RELAXED, __HIP_MEMORY_SCOPE_AGENT);
}
static __device__ __forceinline__ float pollv(unsigned long long* p, unsigned want) {
    unsigned long long pk = __hip_atomic_load(p, __ATOMIC_RELAXED, __HIP_MEMORY_SCOPE_AGENT);
    while ((unsigned)(pk >> 32) != want)
        pk = __hip_atomic_load(p, __ATOMIC_RELAXED, __HIP_MEMORY_SCOPE_AGENT);
    return __uint_as_float((unsigned)(pk & 0xffffffffu));
}

// AGPR move helpers (gfx950: v_accvgpr_read/write, cdna4_isa.md §10)
#define AW(dst, src) asm volatile("v_accvgpr_write_b32 %0, %1" : "=a"(dst) : "v"(src))
#define AR(dst, src) asm volatile("v_accvgpr_read_b32 %0, %1" : "=v"(dst) : "a"(src))

__global__ void __attribute__((amdgpu_flat_work_group_size(512, 512),
                               amdgpu_waves_per_eu(2, 2)))
fused_recur(const float* __restrict__ Whh0, const float* __restrict__ Wih1,
            const float* __restrict__ Whh1, const float* __restrict__ b1,
            float* __restrict__ seq, float* __restrict__ hTout,
            unsigned long long* __restrict__ hb0, unsigned long long* __restrict__ hb1)
{
    __shared__ float lds_a[2][8][64];
    __shared__ float lds_b[2][8][64];
    const int bid  = (int)blockIdx.x;
    const int c    = bid & 31;      // chain; 8 slices of chain c share bid%8 (XCD-local if round-robin)
    const int x    = bid >> 5;      // col-slice 0..7
    const int tid  = (int)threadIdx.x;
    const int lane = tid & 63;
    const int w    = tid >> 6;      // wave id == k-group
    const int J    = (x << 6) + lane;
    const long wb  = (long)(w << 6) * HH + J;   // &M[(w*64+kk)*HH + J], kk stride HH

    // ---- Whh0 slice: 16 named float4s, pinned arch VGPRs (round-8 proven) ----
    float4 wa0,wa1,wa2,wa3,wa4,wa5,wa6,wa7,wa8,wa9,wa10,wa11,wa12,wa13,wa14,wa15;
#define LD1(P, M, q) do { \
        P##q.x = M[wb + (4*q+0)*HH]; P##q.y = M[wb + (4*q+1)*HH]; \
        P##q.z = M[wb + (4*q+2)*HH]; P##q.w = M[wb + (4*q+3)*HH]; } while (0)
    LD1(wa,Whh0,0);  LD1(wa,Whh0,1);  LD1(wa,Whh0,2);  LD1(wa,Whh0,3);
    LD1(wa,Whh0,4);  LD1(wa,Whh0,5);  LD1(wa,Whh0,6);  LD1(wa,Whh0,7);
    LD1(wa,Whh0,8);  LD1(wa,Whh0,9);  LD1(wa,Whh0,10); LD1(wa,Whh0,11);
    LD1(wa,Whh0,12); LD1(wa,Whh0,13); LD1(wa,Whh0,14); LD1(wa,Whh0,15);
#undef LD1
#define PIN1(P, q) asm volatile("" : "+v"(P##q.x), "+v"(P##q.y), "+v"(P##q.z), "+v"(P##q.w))
    PIN1(wa,0);  PIN1(wa,1);  PIN1(wa,2);  PIN1(wa,3);
    PIN1(wa,4);  PIN1(wa,5);  PIN1(wa,6);  PIN1(wa,7);
    PIN1(wa,8);  PIN1(wa,9);  PIN1(wa,10); PIN1(wa,11);
    PIN1(wa,12); PIN1(wa,13); PIN1(wa,14); PIN1(wa,15);
#undef PIN1

    // ---- Wih1 (ai*) and Whh1 (ah*) slices: 128 AGPR-resident floats ----
#define DEFA4(P,q) float P##q##x, P##q##y, P##q##z, P##q##w;
    DEFA4(ai,0)  DEFA4(ai,1)  DEFA4(ai,2)  DEFA4(ai,3)
    DEFA4(ai,4)  DEFA4(ai,5)  DEFA4(ai,6)  DEFA4(ai,7)
    DEFA4(ai,8)  DEFA4(ai,9)  DEFA4(ai,10) DEFA4(ai,11)
    DEFA4(ai,12) DEFA4(ai,13) DEFA4(ai,14) DEFA4(ai,15)
    DEFA4(ah,0)  DEFA4(ah,1)  DEFA4(ah,2)  DEFA4(ah,3)
    DEFA4(ah,4)  DEFA4(ah,5)  DEFA4(ah,6)  DEFA4(ah,7)
    DEFA4(ah,8)  DEFA4(ah,9)  DEFA4(ah,10) DEFA4(ah,11)
    DEFA4(ah,12) DEFA4(ah,13) DEFA4(ah,14) DEFA4(ah,15)
#undef DEFA4
#define STASH4(P, M, q) do { \
        float tx = M[wb + (4*q+0)*HH], ty = M[wb + (4*q+1)*HH], \
              tz = M[wb + (4*q+2)*HH], tw = M[wb + (4*q+3)*HH]; \
        AW(P##q##x, tx); AW(P##q##y, ty); AW(P##q##z, tz); AW(P##q##w, tw); } while (0)
    STASH4(ai,Wih1,0);  STASH4(ai,Wih1,1);  STASH4(ai,Wih1,2);  STASH4(ai,Wih1,3);
    STASH4(ai,Wih1,4);  STASH4(ai,Wih1,5);  STASH4(ai,Wih1,6);  STASH4(ai,Wih1,7);
    STASH4(ai,Wih1,8);  STASH4(ai,Wih1,9);  STASH4(ai,Wih1,10); STASH4(ai,Wih1,11);
    STASH4(ai,Wih1,12); STASH4(ai,Wih1,13); STASH4(ai,Wih1,14); STASH4(ai,Wih1,15);
    STASH4(ah,Whh1,0);  STASH4(ah,Whh1,1);  STASH4(ah,Whh1,2);  STASH4(ah,Whh1,3);
    STASH4(ah,Whh1,4);  STASH4(ah,Whh1,5);  STASH4(ah,Whh1,6);  STASH4(ah,Whh1,7);
    STASH4(ah,Whh1,8);  STASH4(ah,Whh1,9);  STASH4(ah,Whh1,10); STASH4(ah,Whh1,11);
    STASH4(ah,Whh1,12); STASH4(ah,Whh1,13); STASH4(ah,Whh1,14); STASH4(ah,Whh1,15);
#undef STASH4

    unsigned long long* hbc0 = hb0 + c * (2 * HH);   // [2][512] packed {tag|val}
    unsigned long long* hbc1 = hb1 + c * (2 * HH);
    float* rowbase = seq + (long)c * TT * HH;        // pre0 in, h1 out (in-place)

    float pre_cur = 0.f, b1v = 0.f;
    if (tid < 64) { pre_cur = rowbase[J]; b1v = b1[J]; }

    // prologue: h0[0] = tanh(pre0[0]); publish tag 1 (slot 0)
    if (tid < 64) {
        const float hv = tanhx(pre_cur);
        pub(hbc0 + J, 1u, hv);
        pre_cur = rowbase[HH + J];                   // pre0[1]
    }
    float h1reg = 0.f;

#define BC0(i) __uint_as_float(__builtin_amdgcn_readlane(h0bits, (i)))
#define BC1(i) __uint_as_float(__builtin_amdgcn_readlane(h1bits, (i)))

    for (int t = 0; t < TT; ++t) {
        // P3: poll h0[t] (tag t+1, slot t&1) — the one real RTT wait per super-step
        const float h0new = pollv(hbc0 + ((t & 1) << 9) + (w << 6) + lane, (unsigned)(t + 1));
        const unsigned h0bits = __float_as_uint(h0new);

        if (t + 1 < TT) {   // C1: layer-0 step — the critical chain (arch-VGPR W)
            float a0 = 0.f, a1 = 0.f, a2 = 0.f, a3 = 0.f;
#define MACA(q) do { a0 = fmaf(BC0(4*q+0), wa##q.x, a0); a1 = fmaf(BC0(4*q+1), wa##q.y, a1); \
                     a2 = fmaf(BC0(4*q+2), wa##q.z, a2); a3 = fmaf(BC0(4*q+3), wa##q.w, a3); } while (0)
            MACA(0); MACA(1); MACA(2); MACA(3); MACA(4); MACA(5); MACA(6); MACA(7);
            MACA(8); MACA(9); MACA(10); MACA(11); MACA(12); MACA(13); MACA(14); MACA(15);
#undef MACA
            lds_a[(t + 1) & 1][w][lane] = (a0 + a1) + (a2 + a3);
            __syncthreads();
            if (tid < 64) {
                float s = pre_cur;
                #pragma unroll
                for (int q = 0; q < 8; ++q) s += lds_a[(t + 1) & 1][q][lane];
                const float hv = tanhx(s);
                pub(hbc0 + (((t + 1) & 1) << 9) + J, (unsigned)(t + 2), hv);  // publish ASAP
                if (t + 2 < TT) pre_cur = rowbase[(long)(t + 2) * HH + J];
                if (t + 1 == TT - 1) hTout[(c << 9) + J] = hv;                // hT layer 0
            }
        }

        // P2: poll h1[t-1] (tag t, slot (t-1)&1) — published a full super-step ago
        if (t > 0)
            h1reg = pollv(hbc1 + (((t - 1) & 1) << 9) + (w << 6) + lane, (unsigned)t);
        const unsigned h1bits = __float_as_uint(h1reg);

        // C2: layer-1 step (AGPR W; +accvgpr_read latency sits in RTT slack)
        {
            float a0 = 0.f, a1 = 0.f, a2 = 0.f, a3 = 0.f;
#define MACAG(P, BC, q) do { float tx, ty, tz, tw; \
            AR(tx, P##q##x); AR(ty, P##q##y); AR(tz, P##q##z); AR(tw, P##q##w); \
            a0 = fmaf(BC(4*q+0), tx, a0); a1 = fmaf(BC(4*q+1), ty, a1); \
            a2 = fmaf(BC(4*q+2), tz, a2); a3 = fmaf(BC(4*q+3), tw, a3); } while (0)
            MACAG(ai,BC0,0);  MACAG(ai,BC0,1);  MACAG(ai,BC0,2);  MACAG(ai,BC0,3);
            MACAG(ai,BC0,4);  MACAG(ai,BC0,5);  MACAG(ai,BC0,6);  MACAG(ai,BC0,7);
            MACAG(ai,BC0,8);  MACAG(ai,BC0,9);  MACAG(ai,BC0,10); MACAG(ai,BC0,11);
            MACAG(ai,BC0,12); MACAG(ai,BC0,13); MACAG(ai,BC0,14); MACAG(ai,BC0,15);
            MACAG(ah,BC1,0);  MACAG(ah,BC1,1);  MACAG(ah,BC1,2);  MACAG(ah,BC1,3);
            MACAG(ah,BC1,4);  MACAG(ah,BC1,5);  MACAG(ah,BC1,6);  MACAG(ah,BC1,7);
            MACAG(ah,BC1,8);  MACAG(ah,BC1,9);  MACAG(ah,BC1,10); MACAG(ah,BC1,11);
            MACAG(ah,BC1,12); MACAG(ah,BC1,13); MACAG(ah,BC1,14); MACAG(ah,BC1,15);
#undef MACAG
            lds_b[t & 1][w][lane] = (a0 + a1) + (a2 + a3);
            __syncthreads();
            if (tid < 64) {
                float s2 = b1v;
                #pragma unroll
                for (int q = 0; q < 8; ++q) s2 += lds_b[t & 1][q][lane];
                const float h1v = tanhx(s2);
                rowbase[(long)t * HH + J] = h1v;                   // THE output (h1 seq)
                if (t + 1 < TT) pub(hbc1 + ((t & 1) << 9) + J, (unsigned)(t + 1), h1v);
                else hTout[(BB << 9) + (c << 9) + J] = h1v;        // hT layer 1
            }
        }
    }
#undef BC1
#undef BC0
}

extern "C" void kernel_launch(void* const* d_in, const int* in_sizes, int n_in,
                              void* d_out, int out_size, void* d_ws, size_t ws_size,
                              hipStream_t stream) {
    const float* x    = (const float*)d_in[0];
    const float* Wih0 = (const float*)d_in[1];
    const float* Whh0 = (const float*)d_in[2];
    const float* b0   = (const float*)d_in[3];
    const float* Wih1 = (const float*)d_in[4];
    const float* Whh1 = (const float*)d_in[5];
    const float* b1   = (const float*)d_in[6];

    float* out = (float*)d_out;                       // [B,T,H] (h1 seq) + [2,B,H] (hT)
    float* hT  = out + (size_t)BB * TT * HH;

    // ws: hb0 [32][2][512]x8B = 256K, hb1 same at +256K. memset both each call:
    // graph replays reuse ws un-poisoned and stale tags would alias wanted tags.
    unsigned long long* hb0 = (unsigned long long*)d_ws;
    unsigned long long* hb1 = hb0 + (size_t)BB * 2 * HH;
    (void)hipMemsetAsync(d_ws, 0, (size_t)2 * BB * 2 * HH * sizeof(unsigned long long), stream);

    // 1) pre0 = x @ W_ih0 + b0  -> d_out main region (consumed in-place by fused_recur)
    ih_gemm<256><<<dim3((BB * TT) / 32), dim3(256), 0, stream>>>(x, Wih0, b0, out);
    // 2) fused 2-layer recurrence: h1 seq -> d_out (in-place over pre0), hT tails
    fused_recur<<<dim3(256), dim3(512), 0, stream>>>(Whh0, Wih1, Whh1, b1,
                                                     out, hT, hb0, hb1);
}

// Round 11
// 5234.385 us; speedup vs baseline: 1.0501x; 1.0501x over previous
//
#include <hip/hip_runtime.h>
#include <math.h>

#define TT 2048
#define BB 32
#define HH 512

// ---------------- input-projection GEMM: OUT[r,:] = X[r,:]@W + bias ----------------
template<int K>
__global__ void __launch_bounds__(256)
ih_gemm(const float* X, const float* __restrict__ W,
        const float* __restrict__ bias, float* OUT)
{
    __shared__ float xt[32][K];
    const int wg  = (int)blockIdx.x;
    const int tid = (int)threadIdx.x;
    const long row0 = (long)wg * 32;

    {   // stage 32 rows of X (coalesced float4)
        const float4* Xv = (const float4*)(X + row0 * K);
        float4* xtv = (float4*)(&xt[0][0]);
        const int n4 = 8 * K;
        for (int i = tid; i < n4; i += 256) xtv[i] = Xv[i];
    }
    __syncthreads();

    const int j2 = tid * 2;
    float acc0[32], acc1[32];
    #pragma unroll
    for (int r = 0; r < 32; ++r) { acc0[r] = 0.f; acc1[r] = 0.f; }

    for (int k = 0; k < K; k += 4) {
        const float2 w0 = *(const float2*)&W[(k+0)*HH + j2];
        const float2 w1 = *(const float2*)&W[(k+1)*HH + j2];
        const float2 w2 = *(const float2*)&W[(k+2)*HH + j2];
        const float2 w3 = *(const float2*)&W[(k+3)*HH + j2];
        #pragma unroll
        for (int r = 0; r < 32; ++r) {
            const float4 xv = *(const float4*)&xt[r][k];
            acc0[r] += xv.x*w0.x + xv.y*w1.x + xv.z*w2.x + xv.w*w3.x;
            acc1[r] += xv.x*w0.y + xv.y*w1.y + xv.z*w2.y + xv.w*w3.y;
        }
    }
    const float2 bv = *(const float2*)&bias[j2];
    #pragma unroll
    for (int r = 0; r < 32; ++r) {
        float2 o; o.x = acc0[r] + bv.x; o.y = acc1[r] + bv.y;
        *(float2*)&OUT[(row0 + r) * HH + j2] = o;
    }
}

// ---------------- fused 2-layer persistent recurrence ----------------
// Round-9 schedule (PASSED twice; tag-chain + parity-LDS proofs unchanged):
//   body(t): P3 poll h0[t] -> C1: Whh0-MAC+reduce+pub h0[t+1] (critical chain)
//            P2 poll h1[t-1] (1-step slack) -> C2: Wih1/Whh1-MAC+reduce -> h1[t]
//
// Register plan (rounds 8/9/10 evidence):
//  - 192 pinned arch VGPRs -> allocator spills (r9: VGPR 112).
//  - 128 volatile-AGPR reads/step -> serialized, C2 blows the RTT window (r10: +30%).
//  - THIS round: Whh0 + Wih1 = 128 pinned arch (between r8's proven 64 and r9's
//    failing 192); Whh1 = 64 AGPRs, init via volatile v_accvgpr_write, read in C2
//    via NON-volatile v_accvgpr_read (schedulable, interleaves with fma stream).
//    Unified budget at waves_per_eu(2,2): ~168 arch + 64 acc = 232 <= 256.
//  - C2's Wih1 readlanes CSE with C1's (same h0bits) -> C2 ~ 640cy, inside RTT slack.
static __device__ __forceinline__ float tanhx(float s) {
    const float e = __expf(2.0f * s);
    return 1.0f - 2.0f / (e + 1.0f);
}
static __device__ __forceinline__ void pub(unsigned long long* p, unsigned tag, float v) {
    __hip_atomic_store(p, ((unsigned long long)tag << 32) | (unsigned long long)__float_as_uint(v),
                       __ATOMIC_RELAXED, __HIP_MEMORY_SCOPE_AGENT);
}
static __device__ __forceinline__ float pollv(unsigned long long* p, unsigned want) {
    unsigned long long pk = __hip_atomic_load(p, __ATOMIC_RELAXED, __HIP_MEMORY_SCOPE_AGENT);
    while ((unsigned)(pk >> 32) != want)
        pk = __hip_atomic_load(p, __ATOMIC_RELAXED, __HIP_MEMORY_SCOPE_AGENT);
    return __uint_as_float((unsigned)(pk & 0xffffffffu));
}

// AGPR move helpers (gfx950 unified RF). Write: volatile (init-once, must not sink).
// Read: NON-volatile -> the scheduler may interleave/CSE it with the MAC stream.
#define AW(dst, src) asm volatile("v_accvgpr_write_b32 %0, %1" : "=a"(dst) : "v"(src))
#define AR(dst, src) asm("v_accvgpr_read_b32 %0, %1" : "=v"(dst) : "a"(src))

__global__ void __attribute__((amdgpu_flat_work_group_size(512, 512),
                               amdgpu_waves_per_eu(2, 2)))
fused_recur(const float* __restrict__ Whh0, const float* __restrict__ Wih1,
            const float* __restrict__ Whh1, const float* __restrict__ b1,
            float* __restrict__ seq, float* __restrict__ hTout,
            unsigned long long* __restrict__ hb0, unsigned long long* __restrict__ hb1)
{
    __shared__ float lds_a[2][8][64];
    __shared__ float lds_b[2][8][64];
    const int bid  = (int)blockIdx.x;
    const int c    = bid & 31;      // chain; 8 slices of chain c share bid%8 (XCD-local if round-robin)
    const int x    = bid >> 5;      // col-slice 0..7
    const int tid  = (int)threadIdx.x;
    const int lane = tid & 63;
    const int w    = tid >> 6;      // wave id == k-group
    const int J    = (x << 6) + lane;
    const long wb  = (long)(w << 6) * HH + J;   // &M[(w*64+kk)*HH + J], kk stride HH

    // ---- Whh0 (wa*) + Wih1 (wi*): 32 named float4s, pinned arch VGPRs ----
    float4 wa0,wa1,wa2,wa3,wa4,wa5,wa6,wa7,wa8,wa9,wa10,wa11,wa12,wa13,wa14,wa15;
    float4 wi0,wi1,wi2,wi3,wi4,wi5,wi6,wi7,wi8,wi9,wi10,wi11,wi12,wi13,wi14,wi15;
#define LD1(P, M, q) do { \
        P##q.x = M[wb + (4*q+0)*HH]; P##q.y = M[wb + (4*q+1)*HH]; \
        P##q.z = M[wb + (4*q+2)*HH]; P##q.w = M[wb + (4*q+3)*HH]; } while (0)
    LD1(wa,Whh0,0);  LD1(wa,Whh0,1);  LD1(wa,Whh0,2);  LD1(wa,Whh0,3);
    LD1(wa,Whh0,4);  LD1(wa,Whh0,5);  LD1(wa,Whh0,6);  LD1(wa,Whh0,7);
    LD1(wa,Whh0,8);  LD1(wa,Whh0,9);  LD1(wa,Whh0,10); LD1(wa,Whh0,11);
    LD1(wa,Whh0,12); LD1(wa,Whh0,13); LD1(wa,Whh0,14); LD1(wa,Whh0,15);
    LD1(wi,Wih1,0);  LD1(wi,Wih1,1);  LD1(wi,Wih1,2);  LD1(wi,Wih1,3);
    LD1(wi,Wih1,4);  LD1(wi,Wih1,5);  LD1(wi,Wih1,6);  LD1(wi,Wih1,7);
    LD1(wi,Wih1,8);  LD1(wi,Wih1,9);  LD1(wi,Wih1,10); LD1(wi,Wih1,11);
    LD1(wi,Wih1,12); LD1(wi,Wih1,13); LD1(wi,Wih1,14); LD1(wi,Wih1,15);
#undef LD1
#define PIN1(P, q) asm volatile("" : "+v"(P##q.x), "+v"(P##q.y), "+v"(P##q.z), "+v"(P##q.w))
    PIN1(wa,0);  PIN1(wa,1);  PIN1(wa,2);  PIN1(wa,3);
    PIN1(wa,4);  PIN1(wa,5);  PIN1(wa,6);  PIN1(wa,7);
    PIN1(wa,8);  PIN1(wa,9);  PIN1(wa,10); PIN1(wa,11);
    PIN1(wa,12); PIN1(wa,13); PIN1(wa,14); PIN1(wa,15);
    PIN1(wi,0);  PIN1(wi,1);  PIN1(wi,2);  PIN1(wi,3);
    PIN1(wi,4);  PIN1(wi,5);  PIN1(wi,6);  PIN1(wi,7);
    PIN1(wi,8);  PIN1(wi,9);  PIN1(wi,10); PIN1(wi,11);
    PIN1(wi,12); PIN1(wi,13); PIN1(wi,14); PIN1(wi,15);
#undef PIN1

    // ---- Whh1 (ah*): 64 AGPR-resident floats ----
#define DEFA4(P,q) float P##q##x, P##q##y, P##q##z, P##q##w;
    DEFA4(ah,0)  DEFA4(ah,1)  DEFA4(ah,2)  DEFA4(ah,3)
    DEFA4(ah,4)  DEFA4(ah,5)  DEFA4(ah,6)  DEFA4(ah,7)
    DEFA4(ah,8)  DEFA4(ah,9)  DEFA4(ah,10) DEFA4(ah,11)
    DEFA4(ah,12) DEFA4(ah,13) DEFA4(ah,14) DEFA4(ah,15)
#undef DEFA4
#define STASH4(P, M, q) do { \
        float tx = M[wb + (4*q+0)*HH], ty = M[wb + (4*q+1)*HH], \
              tz = M[wb + (4*q+2)*HH], tw = M[wb + (4*q+3)*HH]; \
        AW(P##q##x, tx); AW(P##q##y, ty); AW(P##q##z, tz); AW(P##q##w, tw); } while (0)
    STASH4(ah,Whh1,0);  STASH4(ah,Whh1,1);  STASH4(ah,Whh1,2);  STASH4(ah,Whh1,3);
    STASH4(ah,Whh1,4);  STASH4(ah,Whh1,5);  STASH4(ah,Whh1,6);  STASH4(ah,Whh1,7);
    STASH4(ah,Whh1,8);  STASH4(ah,Whh1,9);  STASH4(ah,Whh1,10); STASH4(ah,Whh1,11);
    STASH4(ah,Whh1,12); STASH4(ah,Whh1,13); STASH4(ah,Whh1,14); STASH4(ah,Whh1,15);
#undef STASH4

    unsigned long long* hbc0 = hb0 + c * (2 * HH);   // [2][512] packed {tag|val}
    unsigned long long* hbc1 = hb1 + c * (2 * HH);
    float* rowbase = seq + (long)c * TT * HH;        // pre0 in, h1 out (in-place)

    float pre_cur = 0.f, b1v = 0.f;
    if (tid < 64) { pre_cur = rowbase[J]; b1v = b1[J]; }

    // prologue: h0[0] = tanh(pre0[0]); publish tag 1 (slot 0)
    if (tid < 64) {
        const float hv = tanhx(pre_cur);
        pub(hbc0 + J, 1u, hv);
        pre_cur = rowbase[HH + J];                   // pre0[1]
    }
    float h1reg = 0.f;

#define BC0(i) __uint_as_float(__builtin_amdgcn_readlane(h0bits, (i)))
#define BC1(i) __uint_as_float(__builtin_amdgcn_readlane(h1bits, (i)))

    for (int t = 0; t < TT; ++t) {
        // P3: poll h0[t] (tag t+1, slot t&1) — the one real RTT wait per super-step
        const float h0new = pollv(hbc0 + ((t & 1) << 9) + (w << 6) + lane, (unsigned)(t + 1));
        const unsigned h0bits = __float_as_uint(h0new);

        if (t + 1 < TT) {   // C1: layer-0 step — the critical chain (arch-VGPR W)
            float a0 = 0.f, a1 = 0.f, a2 = 0.f, a3 = 0.f;
#define MACA(q) do { a0 = fmaf(BC0(4*q+0), wa##q.x, a0); a1 = fmaf(BC0(4*q+1), wa##q.y, a1); \
                     a2 = fmaf(BC0(4*q+2), wa##q.z, a2); a3 = fmaf(BC0(4*q+3), wa##q.w, a3); } while (0)
            MACA(0); MACA(1); MACA(2); MACA(3); MACA(4); MACA(5); MACA(6); MACA(7);
            MACA(8); MACA(9); MACA(10); MACA(11); MACA(12); MACA(13); MACA(14); MACA(15);
#undef MACA
            lds_a[(t + 1) & 1][w][lane] = (a0 + a1) + (a2 + a3);
            __syncthreads();
            if (tid < 64) {
                float s = pre_cur;
                #pragma unroll
                for (int q = 0; q < 8; ++q) s += lds_a[(t + 1) & 1][q][lane];
                const float hv = tanhx(s);
                pub(hbc0 + (((t + 1) & 1) << 9) + J, (unsigned)(t + 2), hv);  // publish ASAP
                if (t + 2 < TT) pre_cur = rowbase[(long)(t + 2) * HH + J];
                if (t + 1 == TT - 1) hTout[(c << 9) + J] = hv;                // hT layer 0
            }
        }

        // P2: poll h1[t-1] (tag t, slot (t-1)&1) — published a full super-step ago
        if (t > 0)
            h1reg = pollv(hbc1 + (((t - 1) & 1) << 9) + (w << 6) + lane, (unsigned)t);
        const unsigned h1bits = __float_as_uint(h1reg);

        // C2: layer-1 step. Wih1 from arch regs (readlanes CSE with C1);
        // Whh1 via non-volatile accvgpr_read, interleaved with the fma stream.
        {
            float a0 = 0.f, a1 = 0.f, a2 = 0.f, a3 = 0.f;
#define MACI(q) do { a0 = fmaf(BC0(4*q+0), wi##q.x, a0); a1 = fmaf(BC0(4*q+1), wi##q.y, a1); \
                     a2 = fmaf(BC0(4*q+2), wi##q.z, a2); a3 = fmaf(BC0(4*q+3), wi##q.w, a3); } while (0)
#define MACH(q) do { float tx, ty, tz, tw; \
            AR(tx, ah##q##x); AR(ty, ah##q##y); AR(tz, ah##q##z); AR(tw, ah##q##w); \
            a0 = fmaf(BC1(4*q+0), tx, a0); a1 = fmaf(BC1(4*q+1), ty, a1); \
            a2 = fmaf(BC1(4*q+2), tz, a2); a3 = fmaf(BC1(4*q+3), tw, a3); } while (0)
            MACI(0); MACI(1); MACI(2); MACI(3); MACI(4); MACI(5); MACI(6); MACI(7);
            MACI(8); MACI(9); MACI(10); MACI(11); MACI(12); MACI(13); MACI(14); MACI(15);
            MACH(0); MACH(1); MACH(2); MACH(3); MACH(4); MACH(5); MACH(6); MACH(7);
            MACH(8); MACH(9); MACH(10); MACH(11); MACH(12); MACH(13); MACH(14); MACH(15);
#undef MACH
#undef MACI
            lds_b[t & 1][w][lane] = (a0 + a1) + (a2 + a3);
            __syncthreads();
            if (tid < 64) {
                float s2 = b1v;
                #pragma unroll
                for (int q = 0; q < 8; ++q) s2 += lds_b[t & 1][q][lane];
                const float h1v = tanhx(s2);
                rowbase[(long)t * HH + J] = h1v;                   // THE output (h1 seq)
                if (t + 1 < TT) pub(hbc1 + ((t & 1) << 9) + J, (unsigned)(t + 1), h1v);
                else hTout[(BB << 9) + (c << 9) + J] = h1v;        // hT layer 1
            }
        }
    }
#undef BC1
#undef BC0
}

extern "C" void kernel_launch(void* const* d_in, const int* in_sizes, int n_in,
                              void* d_out, int out_size, void* d_ws, size_t ws_size,
                              hipStream_t stream) {
    const float* x    = (const float*)d_in[0];
    const float* Wih0 = (const float*)d_in[1];
    const float* Whh0 = (const float*)d_in[2];
    const float* b0   = (const float*)d_in[3];
    const float* Wih1 = (const float*)d_in[4];
    const float* Whh1 = (const float*)d_in[5];
    const float* b1   = (const float*)d_in[6];

    float* out = (float*)d_out;                       // [B,T,H] (h1 seq) + [2,B,H] (hT)
    float* hT  = out + (size_t)BB * TT * HH;

    // ws: hb0 [32][2][512]x8B = 256K, hb1 same at +256K. memset both each call:
    // graph replays reuse ws un-poisoned and stale tags would alias wanted tags.
    unsigned long long* hb0 = (unsigned long long*)d_ws;
    unsigned long long* hb1 = hb0 + (size_t)BB * 2 * HH;
    (void)hipMemsetAsync(d_ws, 0, (size_t)2 * BB * 2 * HH * sizeof(unsigned long long), stream);

    // 1) pre0 = x @ W_ih0 + b0  -> d_out main region (consumed in-place by fused_recur)
    ih_gemm<256><<<dim3((BB * TT) / 32), dim3(256), 0, stream>>>(x, Wih0, b0, out);
    // 2) fused 2-layer recurrence: h1 seq -> d_out (in-place over pre0), hT tails
    fused_recur<<<dim3(256), dim3(512), 0, stream>>>(Whh0, Wih1, Whh1, b1,
                                                     out, hT, hb0, hb1);
}

// Round 12
// 4743.034 us; speedup vs baseline: 1.1589x; 1.1036x over previous
//
#include <hip/hip_runtime.h>
#include <math.h>

#define TT 2048
#define BB 32
#define HH 512

// ---------------- input-projection GEMM: OUT[r,:] = X[r,:]@W + bias ----------------
template<int K>
__global__ void __launch_bounds__(256)
ih_gemm(const float* X, const float* __restrict__ W,
        const float* __restrict__ bias, float* OUT)
{
    __shared__ float xt[32][K];
    const int wg  = (int)blockIdx.x;
    const int tid = (int)threadIdx.x;
    const long row0 = (long)wg * 32;

    {   // stage 32 rows of X (coalesced float4)
        const float4* Xv = (const float4*)(X + row0 * K);
        float4* xtv = (float4*)(&xt[0][0]);
        const int n4 = 8 * K;
        for (int i = tid; i < n4; i += 256) xtv[i] = Xv[i];
    }
    __syncthreads();

    const int j2 = tid * 2;
    float acc0[32], acc1[32];
    #pragma unroll
    for (int r = 0; r < 32; ++r) { acc0[r] = 0.f; acc1[r] = 0.f; }

    for (int k = 0; k < K; k += 4) {
        const float2 w0 = *(const float2*)&W[(k+0)*HH + j2];
        const float2 w1 = *(const float2*)&W[(k+1)*HH + j2];
        const float2 w2 = *(const float2*)&W[(k+2)*HH + j2];
        const float2 w3 = *(const float2*)&W[(k+3)*HH + j2];
        #pragma unroll
        for (int r = 0; r < 32; ++r) {
            const float4 xv = *(const float4*)&xt[r][k];
            acc0[r] += xv.x*w0.x + xv.y*w1.x + xv.z*w2.x + xv.w*w3.x;
            acc1[r] += xv.x*w0.y + xv.y*w1.y + xv.z*w2.y + xv.w*w3.y;
        }
    }
    const float2 bv = *(const float2*)&bias[j2];
    #pragma unroll
    for (int r = 0; r < 32; ++r) {
        float2 o; o.x = acc0[r] + bv.x; o.y = acc1[r] + bv.y;
        *(float2*)&OUT[(row0 + r) * HH + j2] = o;
    }
}

// ---------------- fused 2-layer persistent recurrence ----------------
// Schedule (PASSED r9/r10/r11; tag-chain + parity-LDS proofs unchanged):
//   body(t): P3 poll h0[t] -> C1: Whh0-MAC+reduce+pub h0[t+1] (critical chain)
//            P2 poll h1[t-1] (1-step slack) -> C2: Wih1/Whh1-MAC+reduce -> h1[t]
//
// Storage plan (r9: 192 pinned -> spill; r10: 128 volatile-AGPR -> serialized;
// r11: 128 pinned + 64 AGPR -> granted but slow; FETCH invariant 340MB => stop
// fighting the register file. The idle resource is LDS: 8KB used of 160KB):
//  - Whh0 + Wih1: 128 pinned arch VGPRs (r11 proved 128 pinned is granted).
//  - Whh1 slice (512 k x 64 j = 128 KB): LDS-resident, staged once at entry.
//    Read in C2 as lds_w[k][lane]: consecutive lanes -> consecutive banks,
//    2 lanes/bank aliasing (free on wave64). LDS pipe overlaps the VALU MAC,
//    and these reads don't depend on the polls -> compiler pipelines them.
//  - 1 WG/CU is already forced by waves_per_eu(2,2), so 139KB LDS costs nothing.
static __device__ __forceinline__ float tanhx(float s) {
    const float e = __expf(2.0f * s);
    return 1.0f - 2.0f / (e + 1.0f);
}
static __device__ __forceinline__ void pub(unsigned long long* p, unsigned tag, float v) {
    __hip_atomic_store(p, ((unsigned long long)tag << 32) | (unsigned long long)__float_as_uint(v),
                       __ATOMIC_RELAXED, __HIP_MEMORY_SCOPE_AGENT);
}
static __device__ __forceinline__ float pollv(unsigned long long* p, unsigned want) {
    unsigned long long pk = __hip_atomic_load(p, __ATOMIC_RELAXED, __HIP_MEMORY_SCOPE_AGENT);
    while ((unsigned)(pk >> 32) != want)
        pk = __hip_atomic_load(p, __ATOMIC_RELAXED, __HIP_MEMORY_SCOPE_AGENT);
    return __uint_as_float((unsigned)(pk & 0xffffffffu));
}

__global__ void __attribute__((amdgpu_flat_work_group_size(512, 512),
                               amdgpu_waves_per_eu(2, 2)))
fused_recur(const float* __restrict__ Whh0, const float* __restrict__ Wih1,
            const float* __restrict__ Whh1, const float* __restrict__ b1,
            float* __restrict__ seq, float* __restrict__ hTout,
            unsigned long long* __restrict__ hb0, unsigned long long* __restrict__ hb1)
{
    __shared__ float lds_w[HH][64];        // Whh1 slice: [k][j-local], 128 KB
    __shared__ float lds_a[2][8][64];      // C1 partials (parity dbuf)
    __shared__ float lds_b[2][8][64];      // C2 partials (parity dbuf)
    const int bid  = (int)blockIdx.x;
    const int c    = bid & 31;      // chain; 8 slices of chain c share bid%8
    const int x    = bid >> 5;      // col-slice 0..7
    const int tid  = (int)threadIdx.x;
    const int lane = tid & 63;
    const int w    = tid >> 6;      // wave id == k-group
    const int J    = (x << 6) + lane;
    const long wb  = (long)(w << 6) * HH + J;   // &M[(w*64+kk)*HH + J], kk stride HH

    // ---- stage Whh1 slice into LDS (one-time, coalesced float4) ----
    {
        const int x64 = x << 6;
        for (int idx = tid; idx < HH * 16; idx += 512) {   // 16 float4 per k-row
            const int k  = idx >> 4;
            const int j4 = (idx & 15) << 2;
            *(float4*)&lds_w[k][j4] = *(const float4*)&Whh1[(long)k * HH + x64 + j4];
        }
    }

    // ---- Whh0 (wa*) + Wih1 (wi*): 32 named float4s, pinned arch VGPRs ----
    float4 wa0,wa1,wa2,wa3,wa4,wa5,wa6,wa7,wa8,wa9,wa10,wa11,wa12,wa13,wa14,wa15;
    float4 wi0,wi1,wi2,wi3,wi4,wi5,wi6,wi7,wi8,wi9,wi10,wi11,wi12,wi13,wi14,wi15;
#define LD1(P, M, q) do { \
        P##q.x = M[wb + (4*q+0)*HH]; P##q.y = M[wb + (4*q+1)*HH]; \
        P##q.z = M[wb + (4*q+2)*HH]; P##q.w = M[wb + (4*q+3)*HH]; } while (0)
    LD1(wa,Whh0,0);  LD1(wa,Whh0,1);  LD1(wa,Whh0,2);  LD1(wa,Whh0,3);
    LD1(wa,Whh0,4);  LD1(wa,Whh0,5);  LD1(wa,Whh0,6);  LD1(wa,Whh0,7);
    LD1(wa,Whh0,8);  LD1(wa,Whh0,9);  LD1(wa,Whh0,10); LD1(wa,Whh0,11);
    LD1(wa,Whh0,12); LD1(wa,Whh0,13); LD1(wa,Whh0,14); LD1(wa,Whh0,15);
    LD1(wi,Wih1,0);  LD1(wi,Wih1,1);  LD1(wi,Wih1,2);  LD1(wi,Wih1,3);
    LD1(wi,Wih1,4);  LD1(wi,Wih1,5);  LD1(wi,Wih1,6);  LD1(wi,Wih1,7);
    LD1(wi,Wih1,8);  LD1(wi,Wih1,9);  LD1(wi,Wih1,10); LD1(wi,Wih1,11);
    LD1(wi,Wih1,12); LD1(wi,Wih1,13); LD1(wi,Wih1,14); LD1(wi,Wih1,15);
#undef LD1
#define PIN1(P, q) asm volatile("" : "+v"(P##q.x), "+v"(P##q.y), "+v"(P##q.z), "+v"(P##q.w))
    PIN1(wa,0);  PIN1(wa,1);  PIN1(wa,2);  PIN1(wa,3);
    PIN1(wa,4);  PIN1(wa,5);  PIN1(wa,6);  PIN1(wa,7);
    PIN1(wa,8);  PIN1(wa,9);  PIN1(wa,10); PIN1(wa,11);
    PIN1(wa,12); PIN1(wa,13); PIN1(wa,14); PIN1(wa,15);
    PIN1(wi,0);  PIN1(wi,1);  PIN1(wi,2);  PIN1(wi,3);
    PIN1(wi,4);  PIN1(wi,5);  PIN1(wi,6);  PIN1(wi,7);
    PIN1(wi,8);  PIN1(wi,9);  PIN1(wi,10); PIN1(wi,11);
    PIN1(wi,12); PIN1(wi,13); PIN1(wi,14); PIN1(wi,15);
#undef PIN1

    unsigned long long* hbc0 = hb0 + c * (2 * HH);   // [2][512] packed {tag|val}
    unsigned long long* hbc1 = hb1 + c * (2 * HH);
    float* rowbase = seq + (long)c * TT * HH;        // pre0 in, h1 out (in-place)

    float pre_cur = 0.f, b1v = 0.f;
    if (tid < 64) { pre_cur = rowbase[J]; b1v = b1[J]; }

    __syncthreads();   // lds_w staged before first C2

    // prologue: h0[0] = tanh(pre0[0]); publish tag 1 (slot 0)
    if (tid < 64) {
        const float hv = tanhx(pre_cur);
        pub(hbc0 + J, 1u, hv);
        pre_cur = rowbase[HH + J];                   // pre0[1]
    }
    float h1reg = 0.f;
    const float* lwcol = &lds_w[w << 6][lane];       // my k-block column in LDS

#define BC0(i) __uint_as_float(__builtin_amdgcn_readlane(h0bits, (i)))
#define BC1(i) __uint_as_float(__builtin_amdgcn_readlane(h1bits, (i)))

    for (int t = 0; t < TT; ++t) {
        // P3: poll h0[t] (tag t+1, slot t&1) — the one real RTT wait per super-step
        const float h0new = pollv(hbc0 + ((t & 1) << 9) + (w << 6) + lane, (unsigned)(t + 1));
        const unsigned h0bits = __float_as_uint(h0new);

        if (t + 1 < TT) {   // C1: layer-0 step — the critical chain (arch-VGPR W)
            float a0 = 0.f, a1 = 0.f, a2 = 0.f, a3 = 0.f;
#define MACA(q) do { a0 = fmaf(BC0(4*q+0), wa##q.x, a0); a1 = fmaf(BC0(4*q+1), wa##q.y, a1); \
                     a2 = fmaf(BC0(4*q+2), wa##q.z, a2); a3 = fmaf(BC0(4*q+3), wa##q.w, a3); } while (0)
            MACA(0); MACA(1); MACA(2); MACA(3); MACA(4); MACA(5); MACA(6); MACA(7);
            MACA(8); MACA(9); MACA(10); MACA(11); MACA(12); MACA(13); MACA(14); MACA(15);
#undef MACA
            lds_a[(t + 1) & 1][w][lane] = (a0 + a1) + (a2 + a3);
            __syncthreads();
            if (tid < 64) {
                float s = pre_cur;
                #pragma unroll
                for (int q = 0; q < 8; ++q) s += lds_a[(t + 1) & 1][q][lane];
                const float hv = tanhx(s);
                pub(hbc0 + (((t + 1) & 1) << 9) + J, (unsigned)(t + 2), hv);  // publish ASAP
                if (t + 2 < TT) pre_cur = rowbase[(long)(t + 2) * HH + J];
                if (t + 1 == TT - 1) hTout[(c << 9) + J] = hv;                // hT layer 0
            }
        }

        // P2: poll h1[t-1] (tag t, slot (t-1)&1) — published a full super-step ago
        if (t > 0)
            h1reg = pollv(hbc1 + (((t - 1) & 1) << 9) + (w << 6) + lane, (unsigned)t);
        const unsigned h1bits = __float_as_uint(h1reg);

        // C2: layer-1 step. Wih1 from arch regs (readlanes CSE with C1);
        // Whh1 from LDS (poll-independent reads, pipelined by the compiler).
        {
            float a0 = 0.f, a1 = 0.f, a2 = 0.f, a3 = 0.f;
#define MACI(q) do { a0 = fmaf(BC0(4*q+0), wi##q.x, a0); a1 = fmaf(BC0(4*q+1), wi##q.y, a1); \
                     a2 = fmaf(BC0(4*q+2), wi##q.z, a2); a3 = fmaf(BC0(4*q+3), wi##q.w, a3); } while (0)
#define MACH(q) do { \
            a0 = fmaf(BC1(4*q+0), lwcol[(4*q+0)*64], a0); \
            a1 = fmaf(BC1(4*q+1), lwcol[(4*q+1)*64], a1); \
            a2 = fmaf(BC1(4*q+2), lwcol[(4*q+2)*64], a2); \
            a3 = fmaf(BC1(4*q+3), lwcol[(4*q+3)*64], a3); } while (0)
            MACI(0); MACI(1); MACI(2); MACI(3); MACI(4); MACI(5); MACI(6); MACI(7);
            MACI(8); MACI(9); MACI(10); MACI(11); MACI(12); MACI(13); MACI(14); MACI(15);
            MACH(0); MACH(1); MACH(2); MACH(3); MACH(4); MACH(5); MACH(6); MACH(7);
            MACH(8); MACH(9); MACH(10); MACH(11); MACH(12); MACH(13); MACH(14); MACH(15);
#undef MACH
#undef MACI
            lds_b[t & 1][w][lane] = (a0 + a1) + (a2 + a3);
            __syncthreads();
            if (tid < 64) {
                float s2 = b1v;
                #pragma unroll
                for (int q = 0; q < 8; ++q) s2 += lds_b[t & 1][q][lane];
                const float h1v = tanhx(s2);
                rowbase[(long)t * HH + J] = h1v;                   // THE output (h1 seq)
                if (t + 1 < TT) pub(hbc1 + ((t & 1) << 9) + J, (unsigned)(t + 1), h1v);
                else hTout[(BB << 9) + (c << 9) + J] = h1v;        // hT layer 1
            }
        }
    }
#undef BC1
#undef BC0
}

extern "C" void kernel_launch(void* const* d_in, const int* in_sizes, int n_in,
                              void* d_out, int out_size, void* d_ws, size_t ws_size,
                              hipStream_t stream) {
    const float* x    = (const float*)d_in[0];
    const float* Wih0 = (const float*)d_in[1];
    const float* Whh0 = (const float*)d_in[2];
    const float* b0   = (const float*)d_in[3];
    const float* Wih1 = (const float*)d_in[4];
    const float* Whh1 = (const float*)d_in[5];
    const float* b1   = (const float*)d_in[6];

    float* out = (float*)d_out;                       // [B,T,H] (h1 seq) + [2,B,H] (hT)
    float* hT  = out + (size_t)BB * TT * HH;

    // ws: hb0 [32][2][512]x8B = 256K, hb1 same at +256K. memset both each call:
    // graph replays reuse ws un-poisoned and stale tags would alias wanted tags.
    unsigned long long* hb0 = (unsigned long long*)d_ws;
    unsigned long long* hb1 = hb0 + (size_t)BB * 2 * HH;
    (void)hipMemsetAsync(d_ws, 0, (size_t)2 * BB * 2 * HH * sizeof(unsigned long long), stream);

    // 1) pre0 = x @ W_ih0 + b0  -> d_out main region (consumed in-place by fused_recur)
    ih_gemm<256><<<dim3((BB * TT) / 32), dim3(256), 0, stream>>>(x, Wih0, b0, out);
    // 2) fused 2-layer recurrence: h1 seq -> d_out (in-place over pre0), hT tails
    fused_recur<<<dim3(256), dim3(512), 0, stream>>>(Whh0, Wih1, Whh1, b1,
                                                     out, hT, hb0, hb1);
}